// Round 3
// baseline (7840.960 us; speedup 1.0000x reference)
//
#include <hip/hip_runtime.h>
#include <hip/hip_bf16.h>

typedef __attribute__((ext_vector_type(8))) short short8;
typedef __attribute__((ext_vector_type(4))) float f32x4;

#define DEV __device__ __forceinline__

DEV short f2bf(float f){ __hip_bfloat16 h = __float2bfloat16(f); return *reinterpret_cast<short*>(&h); }
DEV float bf2f(short s){ __hip_bfloat16 h; *reinterpret_cast<short*>(&h) = s; return __bfloat162float(h); }

DEV float sigm(float x){ return 1.f/(1.f + __expf(-x)); }
DEV float tanh_f(float x){
  float ax = fabsf(x);
  float e = __expf(-2.f*ax);
  float t = (1.f - e)/(1.f + e);
  return copysignf(t, x);
}

// ---------------- small utility kernels ----------------

__global__ void k_cvt(const float* __restrict__ in, short* __restrict__ out, long n){
  long i = (long)blockIdx.x*blockDim.x + threadIdx.x;
  long st = (long)gridDim.x*blockDim.x;
  for (; i < n; i += st) out[i] = f2bf(in[i]);
}

// [rows, ic] f32 -> [rows, oc] bf16, zero-padded cols ic..oc (weights only)
__global__ void k_cvt_pad(const float* __restrict__ in, short* __restrict__ out,
                          int rows, int ic, int oc){
  long n = (long)rows*oc;
  long st = (long)gridDim.x*blockDim.x;
  for (long i = (long)blockIdx.x*blockDim.x + threadIdx.x; i < n; i += st){
    int r = (int)(i / oc), c = (int)(i % oc);
    out[i] = (c < ic) ? f2bf(in[(long)r*ic + c]) : (short)0;
  }
}

__global__ void k_bias2(const float* __restrict__ a, const float* __restrict__ b,
                        float* __restrict__ o, int n){
  int i = blockIdx.x*blockDim.x + threadIdx.x;
  if (i < n) o[i] = a[i] + b[i];
}

// exclusive cumsum of sizes[B], B<=1024
__global__ void k_scan(const int* __restrict__ sizes, int* __restrict__ starts, int B){
  __shared__ int t[1024];
  int tid = threadIdx.x;
  int v = (tid < B) ? sizes[tid] : 0;
  t[tid] = v;
  __syncthreads();
  for (int off = 1; off < 1024; off <<= 1){
    int add = (tid >= off) ? t[tid-off] : 0;
    __syncthreads();
    t[tid] += add;
    __syncthreads();
  }
  if (tid < B) starts[tid] = t[tid] - v;
}

// ---------------- generic MFMA GEMM: C = act(A @ B^T + bias) [+ R] ----------------
// A: [M,K] row-major; bf16 (AF32=false) or f32 with true width Ktrue (AF32=true,
// staged+converted+zero-padded to K). B: [N,K] bf16. K%64==0, N%128==0.
template<bool RELU, bool RESID, bool OBF, bool OF32, bool AF32>
__global__ __launch_bounds__(256) void k_gemm(
    const void* __restrict__ Araw, int lda, int Ktrue,
    const short* __restrict__ Bw, int ldb,
    const float* __restrict__ bias,
    const float* __restrict__ R,
    short* __restrict__ Cb, float* __restrict__ Cf, int ldc,
    int M, int N, int K)
{
  constexpr int BM = 64, BN = 128, BK = 64;
  __shared__ short lA[(BK/8)*BM*8];
  __shared__ short lB[(BK/8)*BN*8];
  const short* Ab = (const short*)Araw;
  const float* Af = (const float*)Araw;
  const int tid = threadIdx.x;
  const int l = tid & 63, w = tid >> 6;
  const int lr = l & 15, lk = l >> 4;
  const int bm0 = blockIdx.x*BM, bn0 = blockIdx.y*BN;

  f32x4 acc[4][2];
  #pragma unroll
  for (int a = 0; a < 4; a++)
    #pragma unroll
    for (int b = 0; b < 2; b++) acc[a][b] = (f32x4){0.f,0.f,0.f,0.f};

  for (int k0 = 0; k0 < K; k0 += BK){
    #pragma unroll
    for (int i = 0; i < 2; i++){                  // A: 512 chunks / 256 thr
      int idx = tid + i*256;
      int m = idx >> 3, kc = idx & 7;
      int gm = bm0 + m; if (gm >= M) gm = M-1;
      short8 v;
      if (AF32){
        int kb = k0 + kc*8;
        if (kb + 8 <= Ktrue){
          const float* p = Af + (long)gm*lda + kb;
          float4 f0 = *(const float4*)p;
          float4 f1 = *(const float4*)(p + 4);
          v[0]=f2bf(f0.x); v[1]=f2bf(f0.y); v[2]=f2bf(f0.z); v[3]=f2bf(f0.w);
          v[4]=f2bf(f1.x); v[5]=f2bf(f1.y); v[6]=f2bf(f1.z); v[7]=f2bf(f1.w);
        } else {
          #pragma unroll
          for (int e = 0; e < 8; e++){
            int k = kb + e;
            v[e] = (k < Ktrue) ? f2bf(Af[(long)gm*lda + k]) : (short)0;
          }
        }
      } else {
        v = *(const short8*)(Ab + (long)gm*lda + k0 + kc*8);
      }
      *(short8*)&lA[(kc*BM + m)*8] = v;
    }
    #pragma unroll
    for (int i = 0; i < 4; i++){                  // B: 1024 chunks / 256 thr
      int idx = tid + i*256;
      int n = idx >> 3, kc = idx & 7;
      *(short8*)&lB[(kc*BN + n)*8] = *(const short8*)(Bw + (long)(bn0+n)*ldb + k0 + kc*8);
    }
    __syncthreads();
    #pragma unroll
    for (int kb = 0; kb < 2; kb++){
      short8 af[4], bfv[2];
      #pragma unroll
      for (int mf = 0; mf < 4; mf++)
        af[mf] = *(short8*)&lA[((kb*4+lk)*BM + mf*16 + lr)*8];
      #pragma unroll
      for (int nf = 0; nf < 2; nf++)
        bfv[nf] = *(short8*)&lB[((kb*4+lk)*BN + w*32 + nf*16 + lr)*8];
      #pragma unroll
      for (int mf = 0; mf < 4; mf++)
        #pragma unroll
        for (int nf = 0; nf < 2; nf++)
          acc[mf][nf] = __builtin_amdgcn_mfma_f32_16x16x32_bf16(af[mf], bfv[nf], acc[mf][nf], 0, 0, 0);
    }
    __syncthreads();
  }

  #pragma unroll
  for (int mf = 0; mf < 4; mf++){
    #pragma unroll
    for (int nf = 0; nf < 2; nf++){
      #pragma unroll
      for (int r = 0; r < 4; r++){
        int row = bm0 + mf*16 + lk*4 + r;
        int col = bn0 + w*32 + nf*16 + lr;
        if (row < M){
          float v = acc[mf][nf][r];
          if (bias) v += bias[col];
          if (RELU) v = fmaxf(v, 0.f);
          if (RESID) v += R[(long)row*ldc + col];
          if (OBF) Cb[(long)row*ldc + col] = f2bf(v);
          if (OF32) Cf[(long)row*ldc + col] = v;
        }
      }
    }
  }
}

// ---------------- persistent LSTM with fused input gates ----------------
// Plain launch, 256 blocks x 256 threads, 1 block/CU.
// Group = 16 CONSECUTIVE bids sharing one 64-batch-row tile: bm = bid>>4, ht = bid&15.
// Wave (wr,wc): rows bm*64+wr*32..+32, units ht*32+wc*16..+16, all 4 gates.
// gates = h@Whh^T (Whh frags in 256 VGPRs) + x_t@Wih^T (Wih slice in 128KB LDS,
// x rows gathered per-lane from ragged Xt, zeroed when t >= len) + (bih+bhh).
// c in registers; h ping-pongs via global bf16; per-step 16-block barrier.
__global__ __launch_bounds__(256, 1) void k_lstm(
    const short* __restrict__ Whh,   // [2048,512] bf16
    const short* __restrict__ Wih,   // [2048,512] bf16
    const short* __restrict__ Xt,    // [T,512] bf16 encoded tokens
    short* __restrict__ h0, short* __restrict__ h1,
    float* __restrict__ hF,
    const int* __restrict__ sizes, const int* __restrict__ starts,
    const float* __restrict__ bias2, int* __restrict__ cnt)
{
  __shared__ short wx[4*2*16*64*8];  // [g][wc][kk][lane][8] = 128 KB, frag-major
  const int bid = blockIdx.x;
  const int bm  = bid >> 4;
  const int ht  = bid & 15;
  const int tid = threadIdx.x;
  const int l = tid & 63, wid = tid >> 6;
  const int wr = wid >> 1, wc = wid & 1;
  const int lr = l & 15, lk = l >> 4;
  const int rowbase = bm*64 + wr*32;
  const int j = ht*32 + wc*16 + lr;     // this lane's unit column

  // stage this block's Wih slice into LDS (frag-major, conflict-free reads)
  for (int c = tid; c < 8192; c += 256){
    int lane = c & 63;
    int kk  = (c >> 6) & 15;
    int wcs = (c >> 10) & 1;
    int g   = c >> 11;
    int row = g*512 + ht*32 + wcs*16 + (lane & 15);
    int col = kk*32 + (lane >> 4)*8;
    *(short8*)&wx[(size_t)c*8] = *(const short8*)(Wih + (long)row*512 + col);
  }

  // Whh B-fragments resident in registers
  short8 Breg[4][16];
  #pragma unroll
  for (int g = 0; g < 4; ++g){
    const short* wp = Whh + (long)(g*512 + j)*512 + lk*8;
    #pragma unroll
    for (int kk = 0; kk < 16; ++kk)
      Breg[g][kk] = *(const short8*)(wp + kk*32);
  }

  float bz[4];
  #pragma unroll
  for (int g = 0; g < 4; ++g) bz[g] = bias2[g*512 + j];

  // per-lane ragged info for the two 16-row A tiles this wave owns
  const int len0 = sizes[rowbase + lr];
  const int len1 = sizes[rowbase + 16 + lr];
  const long xb0 = (long)starts[rowbase + lr]*512;
  const long xb1 = (long)starts[rowbase + 16 + lr]*512;

  __syncthreads();  // wx ready

  float cst[2][4] = {{0.f,0.f,0.f,0.f},{0.f,0.f,0.f,0.f}};
  const int cidx = bm*128;
  const short8 z8 = {0,0,0,0,0,0,0,0};
  const int wxw = wc*16*64*8;  // wc offset inside each gate segment

  for (int t = 0; t < 128; ++t){
    const short* hc = (t & 1) ? h1 : h0;
    short*       hn = (t & 1) ? h0 : h1;
    const bool on0 = t < len0, on1 = t < len1;
    const short* ph  = hc + (long)(rowbase + lr)*512 + lk*8;
    const short* px0 = Xt + xb0 + (on0 ? (long)t*512 : 0) + lk*8;
    const short* px1 = Xt + xb1 + (on1 ? (long)t*512 : 0) + lk*8;

    f32x4 acc[2][4];
    #pragma unroll
    for (int mf = 0; mf < 2; ++mf)
      #pragma unroll
      for (int g = 0; g < 4; ++g) acc[mf][g] = (f32x4){0.f,0.f,0.f,0.f};

    #pragma unroll
    for (int kk = 0; kk < 16; ++kk){
      short8 a0 = *(const short8*)(ph + kk*32);
      short8 a1 = *(const short8*)(ph + 16*512 + kk*32);
      short8 x0 = on0 ? *(const short8*)(px0 + kk*32) : z8;
      short8 x1 = on1 ? *(const short8*)(px1 + kk*32) : z8;
      #pragma unroll
      for (int g = 0; g < 4; ++g){
        short8 bx = *(short8*)&wx[g*(2*16*64*8) + wxw + (kk*64 + l)*8];
        acc[0][g] = __builtin_amdgcn_mfma_f32_16x16x32_bf16(a0, Breg[g][kk], acc[0][g], 0, 0, 0);
        acc[0][g] = __builtin_amdgcn_mfma_f32_16x16x32_bf16(x0, bx,          acc[0][g], 0, 0, 0);
        acc[1][g] = __builtin_amdgcn_mfma_f32_16x16x32_bf16(a1, Breg[g][kk], acc[1][g], 0, 0, 0);
        acc[1][g] = __builtin_amdgcn_mfma_f32_16x16x32_bf16(x1, bx,          acc[1][g], 0, 0, 0);
      }
    }

    // activations + state update (C-frag rows use lk; x-gating used lr rows — both exact)
    #pragma unroll
    for (int mf = 0; mf < 2; ++mf)
      #pragma unroll
      for (int r = 0; r < 4; ++r){
        int rb = rowbase + mf*16 + lk*4 + r;
        float ip = acc[mf][0][r] + bz[0];
        float fp = acc[mf][1][r] + bz[1];
        float gp = acc[mf][2][r] + bz[2];
        float op = acc[mf][3][r] + bz[3];
        float cn = sigm(fp)*cst[mf][r] + sigm(ip)*tanh_f(gp);
        float hv = sigm(op)*tanh_f(cn);
        cst[mf][r] = cn;
        hn[(long)rb*512 + j] = f2bf(hv);
        if (t == 127) hF[(long)rb*512 + j] = hv;
      }

    // 16-block group barrier (release/acquire, agent scope)
    __threadfence();
    __syncthreads();
    if (tid == 0){
      __hip_atomic_fetch_add(&cnt[cidx + t], 1, __ATOMIC_RELEASE, __HIP_MEMORY_SCOPE_AGENT);
      while (__hip_atomic_load(&cnt[cidx + t], __ATOMIC_ACQUIRE, __HIP_MEMORY_SCOPE_AGENT) < 16)
        __builtin_amdgcn_s_sleep(2);
    }
    __syncthreads();
    __threadfence();
  }
}

// ---------------- decoder: out[b] = dot(X[b,:512], Wd) + bd ----------------
__global__ __launch_bounds__(256) void k_dec(const float* __restrict__ X,
                                             const float* __restrict__ Wd,
                                             const float* __restrict__ bd,
                                             float* __restrict__ out, int B){
  int w = threadIdx.x >> 6, l = threadIdx.x & 63;
  int row = blockIdx.x*4 + w;
  if (row >= B) return;
  float s = 0.f;
  #pragma unroll
  for (int e = 0; e < 8; e++){
    int j = l + 64*e;
    s += X[(long)row*512 + j]*Wd[j];
  }
  #pragma unroll
  for (int off = 32; off > 0; off >>= 1) s += __shfl_down(s, off);
  if (l == 0) out[row] = s + bd[0];
}

// ---------------- host ----------------

extern "C" void kernel_launch(void* const* d_in, const int* in_sizes, int n_in,
                              void* d_out, int out_size, void* d_ws, size_t ws_size,
                              hipStream_t stream)
{
  const int*   sizes = (const int*)  d_in[0];
  const float* feat  = (const float*)d_in[1];
  const float* We0   = (const float*)d_in[2];
  const float* be0   = (const float*)d_in[3];
  const float* We1   = (const float*)d_in[4];
  const float* be1   = (const float*)d_in[5];
  const float* Wih   = (const float*)d_in[6];
  const float* bih   = (const float*)d_in[7];
  const float* Whh   = (const float*)d_in[8];
  const float* bhh   = (const float*)d_in[9];
  const float* Wl0   = (const float*)d_in[10];
  const float* bl0   = (const float*)d_in[11];
  const float* Wl1   = (const float*)d_in[12];
  const float* bl1   = (const float*)d_in[13];
  const float* Wd    = (const float*)d_in[14];
  const float* bd    = (const float*)d_in[15];

  const int B = in_sizes[0];            // 1024
  const int T = in_sizes[1] / 164;      // ragged token count (~65k)
  const int HID = 512;

  char* base = (char*)d_ws;
  size_t off = 0;
  auto alloc = [&](size_t bytes)->char*{
    char* p = base + off;
    off = (off + bytes + 255) & ~(size_t)255;
    return p;
  };

  int*   starts = (int*)  alloc((size_t)B*4);
  float* bias2  = (float*)alloc(2048*4);
  int*   cnt    = (int*)  alloc(16*128*4);
  short* We0b   = (short*)alloc((size_t)512*192*2);
  short* We1b   = (short*)alloc((size_t)512*512*2);
  short* Wihb   = (short*)alloc((size_t)2048*512*2);
  short* Whhb   = (short*)alloc((size_t)2048*512*2);
  short* Wl0b   = (short*)alloc((size_t)512*512*2);
  short* Wl1b   = (short*)alloc((size_t)512*512*2);
  short* hA     = (short*)alloc((size_t)B*HID*2);
  short* hB     = (short*)alloc((size_t)B*HID*2);
  float* hF     = (float*)alloc((size_t)B*HID*4);
  float* r1     = (float*)alloc((size_t)B*HID*4);
  short* r1b    = (short*)alloc((size_t)B*HID*2);
  float* r2     = (float*)alloc((size_t)B*HID*4);
  short* X0b    = (short*)alloc((size_t)T*512*2);   // ~67 MB
  short* Xb     = (short*)alloc((size_t)T*512*2);   // ~67 MB
  (void)ws_size; (void)n_in; (void)out_size;        // total ~147 MB

  hipMemsetAsync(hA,  0, (size_t)B*HID*2, stream);
  hipMemsetAsync(cnt, 0, (size_t)16*128*4, stream);

  k_scan<<<1, 1024, 0, stream>>>(sizes, starts, B);
  k_bias2<<<8, 256, 0, stream>>>(bih, bhh, bias2, 2048);

  auto grd = [](long n){ long g = (n + 255)/256; return (int)(g > 4096 ? 4096 : g); };
  k_cvt_pad<<<grd(512l*192), 256, 0, stream>>>(We0, We0b, 512, 164, 192);
  k_cvt<<<grd(512l*512), 256, 0, stream>>>(We1, We1b, 512l*512);
  k_cvt<<<grd(2048l*512), 256, 0, stream>>>(Wih, Wihb, 2048l*512);
  k_cvt<<<grd(2048l*512), 256, 0, stream>>>(Whh, Whhb, 2048l*512);
  k_cvt<<<grd(512l*512), 256, 0, stream>>>(Wl0, Wl0b, 512l*512);
  k_cvt<<<grd(512l*512), 256, 0, stream>>>(Wl1, Wl1b, 512l*512);

  int mt = (T + 63)/64;
  // encoder layer 0: X0 = relu(feat @ We0^T + be0), f32 A staged+converted, K 164->192
  k_gemm<true,false,true,false,true><<<dim3(mt, 4), 256, 0, stream>>>(
      (const void*)feat, 164, 164, We0b, 192, be0, nullptr, X0b, nullptr, 512, T, 512, 192);
  // encoder layer 1: X = relu(X0 @ We1^T + be1)
  k_gemm<true,false,true,false,false><<<dim3(mt, 4), 256, 0, stream>>>(
      (const void*)X0b, 512, 512, We1b, 512, be1, nullptr, Xb, nullptr, 512, T, 512, 512);

  // persistent LSTM (plain launch, graph-capturable; 16-block groups self-sync)
  k_lstm<<<256, 256, 0, stream>>>(Whhb, Wihb, Xb, hA, hB, hF,
                                  sizes, starts, bias2, cnt);

  // residual MLPs (fp32 residual path, bf16 matmul inputs); final h in hA (bf16) / hF (f32)
  k_gemm<true,true,true,true,false><<<dim3(16, 4), 256, 0, stream>>>(
      (const void*)hA, 512, 512, Wl0b, 512, bl0, hF, r1b, r1, 512, B, 512, 512);
  k_gemm<true,true,false,true,false><<<dim3(16, 4), 256, 0, stream>>>(
      (const void*)r1b, 512, 512, Wl1b, 512, bl1, r1, nullptr, r2, 512, B, 512, 512);

  // decoder
  k_dec<<<B/4, 256, 0, stream>>>(r2, Wd, bd, (float*)d_out, B);
}

// Round 4
// 2267.046 us; speedup vs baseline: 3.4587x; 3.4587x over previous
//
#include <hip/hip_runtime.h>
#include <hip/hip_bf16.h>

typedef __attribute__((ext_vector_type(8))) short short8;
typedef __attribute__((ext_vector_type(4))) float f32x4;

#define DEV __device__ __forceinline__

DEV short f2bf(float f){ __hip_bfloat16 h = __float2bfloat16(f); return *reinterpret_cast<short*>(&h); }
DEV float bf2f(short s){ __hip_bfloat16 h; *reinterpret_cast<short*>(&h) = s; return __bfloat162float(h); }

DEV float sigm(float x){ return 1.f/(1.f + __expf(-x)); }
DEV float tanh_f(float x){
  float ax = fabsf(x);
  float e = __expf(-2.f*ax);
  float t = (1.f - e)/(1.f + e);
  return copysignf(t, x);
}

// LLC-coherent (agent-scope, relaxed) 16B load: two 8B atomic loads.
DEV short8 llc_ld16(const short* p){
  union { unsigned long long u[2]; short8 v; } r;
  r.u[0] = __hip_atomic_load((const unsigned long long*)p,
                             __ATOMIC_RELAXED, __HIP_MEMORY_SCOPE_AGENT);
  r.u[1] = __hip_atomic_load((const unsigned long long*)(p + 4),
                             __ATOMIC_RELAXED, __HIP_MEMORY_SCOPE_AGENT);
  return r.v;
}

// ---------------- small utility kernels ----------------

__global__ void k_cvt(const float* __restrict__ in, short* __restrict__ out, long n){
  long i = (long)blockIdx.x*blockDim.x + threadIdx.x;
  long st = (long)gridDim.x*blockDim.x;
  for (; i < n; i += st) out[i] = f2bf(in[i]);
}

__global__ void k_cvt_pad(const float* __restrict__ in, short* __restrict__ out,
                          int rows, int ic, int oc){
  long n = (long)rows*oc;
  long st = (long)gridDim.x*blockDim.x;
  for (long i = (long)blockIdx.x*blockDim.x + threadIdx.x; i < n; i += st){
    int r = (int)(i / oc), c = (int)(i % oc);
    out[i] = (c < ic) ? f2bf(in[(long)r*ic + c]) : (short)0;
  }
}

__global__ void k_bias2(const float* __restrict__ a, const float* __restrict__ b,
                        float* __restrict__ o, int n){
  int i = blockIdx.x*blockDim.x + threadIdx.x;
  if (i < n) o[i] = a[i] + b[i];
}

// exclusive cumsum of sizes[B], B<=1024
__global__ void k_scan(const int* __restrict__ sizes, int* __restrict__ starts, int B){
  __shared__ int t[1024];
  int tid = threadIdx.x;
  int v = (tid < B) ? sizes[tid] : 0;
  t[tid] = v;
  __syncthreads();
  for (int off = 1; off < 1024; off <<= 1){
    int add = (tid >= off) ? t[tid-off] : 0;
    __syncthreads();
    t[tid] += add;
    __syncthreads();
  }
  if (tid < B) starts[tid] = t[tid] - v;
}

// ---------------- generic MFMA GEMM: C = act(A @ B^T + bias) [+ R] ----------------
template<bool RELU, bool RESID, bool OBF, bool OF32, bool AF32>
__global__ __launch_bounds__(256) void k_gemm(
    const void* __restrict__ Araw, int lda, int Ktrue,
    const short* __restrict__ Bw, int ldb,
    const float* __restrict__ bias,
    const float* __restrict__ R,
    short* __restrict__ Cb, float* __restrict__ Cf, int ldc,
    int M, int N, int K)
{
  constexpr int BM = 64, BN = 128, BK = 64;
  __shared__ short lA[(BK/8)*BM*8];
  __shared__ short lB[(BK/8)*BN*8];
  const short* Ab = (const short*)Araw;
  const float* Af = (const float*)Araw;
  const int tid = threadIdx.x;
  const int l = tid & 63, w = tid >> 6;
  const int lr = l & 15, lk = l >> 4;
  const int bm0 = blockIdx.x*BM, bn0 = blockIdx.y*BN;

  f32x4 acc[4][2];
  #pragma unroll
  for (int a = 0; a < 4; a++)
    #pragma unroll
    for (int b = 0; b < 2; b++) acc[a][b] = (f32x4){0.f,0.f,0.f,0.f};

  for (int k0 = 0; k0 < K; k0 += BK){
    #pragma unroll
    for (int i = 0; i < 2; i++){                  // A: 512 chunks / 256 thr
      int idx = tid + i*256;
      int m = idx >> 3, kc = idx & 7;
      int gm = bm0 + m; if (gm >= M) gm = M-1;
      short8 v;
      if (AF32){
        int kb = k0 + kc*8;
        if (kb + 8 <= Ktrue){
          const float* p = Af + (long)gm*lda + kb;
          float4 f0 = *(const float4*)p;
          float4 f1 = *(const float4*)(p + 4);
          v[0]=f2bf(f0.x); v[1]=f2bf(f0.y); v[2]=f2bf(f0.z); v[3]=f2bf(f0.w);
          v[4]=f2bf(f1.x); v[5]=f2bf(f1.y); v[6]=f2bf(f1.z); v[7]=f2bf(f1.w);
        } else {
          #pragma unroll
          for (int e = 0; e < 8; e++){
            int k = kb + e;
            v[e] = (k < Ktrue) ? f2bf(Af[(long)gm*lda + k]) : (short)0;
          }
        }
      } else {
        v = *(const short8*)(Ab + (long)gm*lda + k0 + kc*8);
      }
      *(short8*)&lA[(kc*BM + m)*8] = v;
    }
    #pragma unroll
    for (int i = 0; i < 4; i++){                  // B: 1024 chunks / 256 thr
      int idx = tid + i*256;
      int n = idx >> 3, kc = idx & 7;
      *(short8*)&lB[(kc*BN + n)*8] = *(const short8*)(Bw + (long)(bn0+n)*ldb + k0 + kc*8);
    }
    __syncthreads();
    #pragma unroll
    for (int kb = 0; kb < 2; kb++){
      short8 af[4], bfv[2];
      #pragma unroll
      for (int mf = 0; mf < 4; mf++)
        af[mf] = *(short8*)&lA[((kb*4+lk)*BM + mf*16 + lr)*8];
      #pragma unroll
      for (int nf = 0; nf < 2; nf++)
        bfv[nf] = *(short8*)&lB[((kb*4+lk)*BN + w*32 + nf*16 + lr)*8];
      #pragma unroll
      for (int mf = 0; mf < 4; mf++)
        #pragma unroll
        for (int nf = 0; nf < 2; nf++)
          acc[mf][nf] = __builtin_amdgcn_mfma_f32_16x16x32_bf16(af[mf], bfv[nf], acc[mf][nf], 0, 0, 0);
    }
    __syncthreads();
  }

  #pragma unroll
  for (int mf = 0; mf < 4; mf++){
    #pragma unroll
    for (int nf = 0; nf < 2; nf++){
      #pragma unroll
      for (int r = 0; r < 4; r++){
        int row = bm0 + mf*16 + lk*4 + r;
        int col = bn0 + w*32 + nf*16 + lr;
        if (row < M){
          float v = acc[mf][nf][r];
          if (bias) v += bias[col];
          if (RELU) v = fmaxf(v, 0.f);
          if (RESID) v += R[(long)row*ldc + col];
          if (OBF) Cb[(long)row*ldc + col] = f2bf(v);
          if (OF32) Cf[(long)row*ldc + col] = v;
        }
      }
    }
  }
}

// ---------------- persistent LSTM with fused input gates ----------------
// 256 blocks x 256 threads, 1 block/CU. XCD-local groups of 16:
//   xcd = bid&7, q = bid>>3, ht = q&15, bm = ((q>>4)<<3)|xcd.
// Wave (wr,wc): rows bm*64+wr*32..+32, units ht*32+wc*16..+16, all 4 gates.
// h exchanged through the LLC ONLY: relaxed agent-scope atomic stores (4B,
// lane-pair packed) and loads (8B). No acquire/release fences anywhere in the
// step loop -> L2/L1 keep Xt, Wih, Whh resident. Barrier: relaxed fetch_add +
// relaxed spin (s_sleep backoff). x-part MFMAs run before the spin.
__global__ __launch_bounds__(256, 1) void k_lstm(
    const short* __restrict__ Whh,   // [2048,512] bf16
    const short* __restrict__ Wih,   // [2048,512] bf16
    const short* __restrict__ Xt,    // [T,512] bf16 encoded tokens
    short* __restrict__ h0, short* __restrict__ h1,
    float* __restrict__ hF,
    const int* __restrict__ sizes, const int* __restrict__ starts,
    const float* __restrict__ bias2, unsigned int* __restrict__ cnt)
{
  __shared__ short wx[4*2*16*64*8];  // [g][wc][kk][lane][8] = 128 KB, frag-major
  const int bid = blockIdx.x;
  const int xcd = bid & 7;
  const int q   = bid >> 3;
  const int ht  = q & 15;
  const int bm  = ((q >> 4) << 3) | xcd;
  const int tid = threadIdx.x;
  const int l = tid & 63, wid = tid >> 6;
  const int wr = wid >> 1, wc = wid & 1;
  const int lr = l & 15, lk = l >> 4;
  const int rowbase = bm*64 + wr*32;
  const int j = ht*32 + wc*16 + lr;     // this lane's unit column

  // stage this block's Wih slice into LDS (frag-major, conflict-free reads)
  for (int c = tid; c < 8192; c += 256){
    int lane = c & 63;
    int kk  = (c >> 6) & 15;
    int wcs = (c >> 10) & 1;
    int g   = c >> 11;
    int row = g*512 + ht*32 + wcs*16 + (lane & 15);
    int col = kk*32 + (lane >> 4)*8;
    *(short8*)&wx[(size_t)c*8] = *(const short8*)(Wih + (long)row*512 + col);
  }

  // Whh B-fragments resident in registers/AGPRs
  short8 Breg[4][16];
  #pragma unroll
  for (int g = 0; g < 4; ++g){
    const short* wp = Whh + (long)(g*512 + j)*512 + lk*8;
    #pragma unroll
    for (int kk = 0; kk < 16; ++kk)
      Breg[g][kk] = *(const short8*)(wp + kk*32);
  }

  float bz[4];
  #pragma unroll
  for (int g = 0; g < 4; ++g) bz[g] = bias2[g*512 + j];

  // per-lane ragged info for the two 16-row A tiles this wave owns
  const int len0 = sizes[rowbase + lr];
  const int len1 = sizes[rowbase + 16 + lr];
  const long xb0 = (long)starts[rowbase + lr]*512;
  const long xb1 = (long)starts[rowbase + 16 + lr]*512;

  __syncthreads();  // wx ready

  float cst[2][4] = {{0.f,0.f,0.f,0.f},{0.f,0.f,0.f,0.f}};
  const int cidx = bm*128;
  const short8 z8 = {0,0,0,0,0,0,0,0};
  const int wxw = wc*16*64*8;

  #pragma unroll 1
  for (int t = 0; t < 128; ++t){
    const short* hc = (t & 1) ? h1 : h0;
    short*       hn = (t & 1) ? h0 : h1;
    const bool on0 = t < len0, on1 = t < len1;
    const short* px0 = Xt + xb0 + (on0 ? (long)t*512 : 0) + lk*8;
    const short* px1 = Xt + xb1 + (on1 ? (long)t*512 : 0) + lk*8;

    f32x4 acc[2][4];
    #pragma unroll
    for (int mf = 0; mf < 2; ++mf)
      #pragma unroll
      for (int g = 0; g < 4; ++g) acc[mf][g] = (f32x4){0.f,0.f,0.f,0.f};

    // ---- x-part (independent of h_t; overlaps the group barrier) ----
    #pragma unroll
    for (int kk = 0; kk < 16; ++kk){
      short8 x0 = on0 ? *(const short8*)(px0 + kk*32) : z8;
      short8 x1 = on1 ? *(const short8*)(px1 + kk*32) : z8;
      #pragma unroll
      for (int g = 0; g < 4; ++g){
        short8 bx = *(short8*)&wx[g*(2*16*64*8) + wxw + (kk*64 + l)*8];
        acc[0][g] = __builtin_amdgcn_mfma_f32_16x16x32_bf16(x0, bx, acc[0][g], 0, 0, 0);
        acc[1][g] = __builtin_amdgcn_mfma_f32_16x16x32_bf16(x1, bx, acc[1][g], 0, 0, 0);
      }
    }

    // ---- wait for h_t, then h-part ----
    if (t > 0){
      while (__hip_atomic_load(&cnt[cidx + t - 1], __ATOMIC_RELAXED,
                               __HIP_MEMORY_SCOPE_AGENT) < 16u)
        __builtin_amdgcn_s_sleep(1);
      asm volatile("" ::: "memory");            // compiler ordering only
      __builtin_amdgcn_sched_barrier(0);

      const short* ph = hc + (long)(rowbase + lr)*512 + lk*8;
      #pragma unroll
      for (int kk = 0; kk < 16; ++kk){
        short8 a0 = llc_ld16(ph + kk*32);
        short8 a1 = llc_ld16(ph + 16*512 + kk*32);
        #pragma unroll
        for (int g = 0; g < 4; ++g){
          acc[0][g] = __builtin_amdgcn_mfma_f32_16x16x32_bf16(a0, Breg[g][kk], acc[0][g], 0, 0, 0);
          acc[1][g] = __builtin_amdgcn_mfma_f32_16x16x32_bf16(a1, Breg[g][kk], acc[1][g], 0, 0, 0);
        }
      }
    }

    // ---- activations + state update + packed LLC store of h_{t+1} ----
    #pragma unroll
    for (int mf = 0; mf < 2; ++mf)
      #pragma unroll
      for (int r = 0; r < 4; ++r){
        int rb = rowbase + mf*16 + lk*4 + r;
        float ip = acc[mf][0][r] + bz[0];
        float fp = acc[mf][1][r] + bz[1];
        float gp = acc[mf][2][r] + bz[2];
        float op = acc[mf][3][r] + bz[3];
        float cn = sigm(fp)*cst[mf][r] + sigm(ip)*tanh_f(gp);
        float hv = sigm(op)*tanh_f(cn);
        cst[mf][r] = cn;
        unsigned int x16 = (unsigned short)f2bf(hv);
        unsigned int par = (unsigned int)__shfl_xor((int)x16, 1, 64);
        if (!(lr & 1)){
          unsigned int wv = x16 | (par << 16);
          __hip_atomic_store((unsigned int*)(hn + (long)rb*512 + (j & ~1)), wv,
                             __ATOMIC_RELAXED, __HIP_MEMORY_SCOPE_AGENT);
        }
        if (t == 127) hF[(long)rb*512 + j] = hv;
      }

    // ---- signal: all stores at LLC, then one relaxed add per block ----
    asm volatile("s_waitcnt vmcnt(0) lgkmcnt(0)" ::: "memory");
    __syncthreads();
    if (tid == 0)
      __hip_atomic_fetch_add(&cnt[cidx + t], 1u, __ATOMIC_RELAXED,
                             __HIP_MEMORY_SCOPE_AGENT);
  }
}

// ---------------- decoder: out[b] = dot(X[b,:512], Wd) + bd ----------------
__global__ __launch_bounds__(256) void k_dec(const float* __restrict__ X,
                                             const float* __restrict__ Wd,
                                             const float* __restrict__ bd,
                                             float* __restrict__ out, int B){
  int w = threadIdx.x >> 6, l = threadIdx.x & 63;
  int row = blockIdx.x*4 + w;
  if (row >= B) return;
  float s = 0.f;
  #pragma unroll
  for (int e = 0; e < 8; e++){
    int j = l + 64*e;
    s += X[(long)row*512 + j]*Wd[j];
  }
  #pragma unroll
  for (int off = 32; off > 0; off >>= 1) s += __shfl_down(s, off);
  if (l == 0) out[row] = s + bd[0];
}

// ---------------- host ----------------

extern "C" void kernel_launch(void* const* d_in, const int* in_sizes, int n_in,
                              void* d_out, int out_size, void* d_ws, size_t ws_size,
                              hipStream_t stream)
{
  const int*   sizes = (const int*)  d_in[0];
  const float* feat  = (const float*)d_in[1];
  const float* We0   = (const float*)d_in[2];
  const float* be0   = (const float*)d_in[3];
  const float* We1   = (const float*)d_in[4];
  const float* be1   = (const float*)d_in[5];
  const float* Wih   = (const float*)d_in[6];
  const float* bih   = (const float*)d_in[7];
  const float* Whh   = (const float*)d_in[8];
  const float* bhh   = (const float*)d_in[9];
  const float* Wl0   = (const float*)d_in[10];
  const float* bl0   = (const float*)d_in[11];
  const float* Wl1   = (const float*)d_in[12];
  const float* bl1   = (const float*)d_in[13];
  const float* Wd    = (const float*)d_in[14];
  const float* bd    = (const float*)d_in[15];

  const int B = in_sizes[0];            // 1024
  const int T = in_sizes[1] / 164;      // ragged token count (~65k)
  const int HID = 512;

  char* base = (char*)d_ws;
  size_t off = 0;
  auto alloc = [&](size_t bytes)->char*{
    char* p = base + off;
    off = (off + bytes + 255) & ~(size_t)255;
    return p;
  };

  int*          starts = (int*)         alloc((size_t)B*4);
  float*        bias2  = (float*)       alloc(2048*4);
  unsigned int* cnt    = (unsigned int*)alloc(16*128*4);
  short* We0b   = (short*)alloc((size_t)512*192*2);
  short* We1b   = (short*)alloc((size_t)512*512*2);
  short* Wihb   = (short*)alloc((size_t)2048*512*2);
  short* Whhb   = (short*)alloc((size_t)2048*512*2);
  short* Wl0b   = (short*)alloc((size_t)512*512*2);
  short* Wl1b   = (short*)alloc((size_t)512*512*2);
  short* hA     = (short*)alloc((size_t)B*HID*2);
  short* hB     = (short*)alloc((size_t)B*HID*2);
  float* hF     = (float*)alloc((size_t)B*HID*4);
  float* r1     = (float*)alloc((size_t)B*HID*4);
  short* r1b    = (short*)alloc((size_t)B*HID*2);
  float* r2     = (float*)alloc((size_t)B*HID*4);
  short* X0b    = (short*)alloc((size_t)T*512*2);   // ~67 MB
  short* Xb     = (short*)alloc((size_t)T*512*2);   // ~67 MB
  (void)ws_size; (void)n_in; (void)out_size;

  hipMemsetAsync(cnt, 0, (size_t)16*128*4, stream);

  k_scan<<<1, 1024, 0, stream>>>(sizes, starts, B);
  k_bias2<<<8, 256, 0, stream>>>(bih, bhh, bias2, 2048);

  auto grd = [](long n){ long g = (n + 255)/256; return (int)(g > 4096 ? 4096 : g); };
  k_cvt_pad<<<grd(512l*192), 256, 0, stream>>>(We0, We0b, 512, 164, 192);
  k_cvt<<<grd(512l*512), 256, 0, stream>>>(We1, We1b, 512l*512);
  k_cvt<<<grd(2048l*512), 256, 0, stream>>>(Wih, Wihb, 2048l*512);
  k_cvt<<<grd(2048l*512), 256, 0, stream>>>(Whh, Whhb, 2048l*512);
  k_cvt<<<grd(512l*512), 256, 0, stream>>>(Wl0, Wl0b, 512l*512);
  k_cvt<<<grd(512l*512), 256, 0, stream>>>(Wl1, Wl1b, 512l*512);

  int mt = (T + 63)/64;
  // encoder layer 0: X0 = relu(feat @ We0^T + be0), f32 A staged+converted, K 164->192
  k_gemm<true,false,true,false,true><<<dim3(mt, 4), 256, 0, stream>>>(
      (const void*)feat, 164, 164, We0b, 192, be0, nullptr, X0b, nullptr, 512, T, 512, 192);
  // encoder layer 1: X = relu(X0 @ We1^T + be1)
  k_gemm<true,false,true,false,false><<<dim3(mt, 4), 256, 0, stream>>>(
      (const void*)X0b, 512, 512, We1b, 512, be1, nullptr, Xb, nullptr, 512, T, 512, 512);

  // persistent LSTM (plain launch; 16-block XCD-local groups self-sync via LLC)
  k_lstm<<<256, 256, 0, stream>>>(Whhb, Wihb, Xb, hA, hB, hF,
                                  sizes, starts, bias2, cnt);

  // residual MLPs; final h read from hF (plain f32 stores -> no coherence hazard)
  k_gemm<true,true,true,true,true><<<dim3(16, 4), 256, 0, stream>>>(
      (const void*)hF, 512, 512, Wl0b, 512, bl0, hF, r1b, r1, 512, B, 512, 512);
  k_gemm<true,true,false,true,false><<<dim3(16, 4), 256, 0, stream>>>(
      (const void*)r1b, 512, 512, Wl1b, 512, bl1, r1, nullptr, r2, 512, B, 512, 512);

  // decoder
  k_dec<<<B/4, 256, 0, stream>>>(r2, Wd, bd, (float*)d_out, B);
}